// Round 4
// baseline (130.504 us; speedup 1.0000x reference)
//
#include <hip/hip_runtime.h>
#include <hip/hip_bf16.h>

// Problem constants
static constexpr int Bn = 8, Cn = 128, Hn = 64, Wn = 64, Con = 128;
static constexpr int KKn = 9, DGn = 2, Cgn = 64;
static constexpr int HOn = 64, WOn = 64;
static constexpr int PITCH = 72;     // bf16 row pitch for LDS val tiles
static constexpr int OMP = 34;       // s_om row pitch (shorts)

// workspace layout
static constexpr size_t XT_BYTES   = 8388608;                       // x_t bf16
static constexpr size_t WT2_BYTES  = 294912;                        // main W frags
static constexpr size_t OWF_BYTES  = 73728;                         // offset W frags
static constexpr size_t VAL2_BYTES = (size_t)18 * 32768 * 64 * 2;   // 75,497,472
static constexpr size_t WS_NEEDED  = XT_BYTES + WT2_BYTES + OWF_BYTES + VAL2_BYTES;

typedef short short8 __attribute__((ext_vector_type(8)));
typedef float f32x4  __attribute__((ext_vector_type(4)));

__device__ __forceinline__ unsigned short f2bf(float f) {
    unsigned u = __float_as_uint(f);
    u += 0x7fff + ((u >> 16) & 1);          // round-to-nearest-even
    return (unsigned short)(u >> 16);
}
__device__ __forceinline__ float bf2f(unsigned short h) {
    return __uint_as_float(((unsigned)h) << 16);
}

// ---------------------------------------------------------------------------
// Kernel P: merged prep (unchanged).
// ---------------------------------------------------------------------------
__global__ __launch_bounds__(256) void prep(const float* __restrict__ x,
                                            const float* __restrict__ w,
                                            const float* __restrict__ ow,
                                            unsigned short* __restrict__ xt,
                                            unsigned short* __restrict__ wt2,
                                            unsigned short* __restrict__ owf) {
    __shared__ unsigned short s[128 * 64];       // 16 KB [c][x]
    const int blk = blockIdx.x;
    const int t = threadIdx.x;
    if (blk < 512) {
        const int b = blk & 7, y = blk >> 3;
#pragma unroll
        for (int i = 0; i < 32; ++i) {
            int e = t + i * 256;                 // [0,8192)
            int c = e >> 6, xc = e & 63;
            s[c * 64 + xc] = f2bf(x[(((size_t)b * Cn + c) * Hn + y) * Wn + xc]);
        }
        __syncthreads();
        unsigned short* dst = xt + ((size_t)(b * 64 + y) * 64) * 128;
#pragma unroll
        for (int i = 0; i < 4; ++i) {
            int e = t + i * 256;                 // short8 id [0,1024)
            int xc = e >> 4;
            int c0 = (e & 15) * 8;
            short8 v;
#pragma unroll
            for (int j = 0; j < 8; ++j) v[j] = (short)s[(c0 + j) * 64 + xc];
            *(short8*)&dst[(size_t)e * 8] = v;
        }
    } else if (blk < 1088) {
        int e    = (blk - 512) * 256 + t;        // [0,147456)
        int j    = e & 7;
        int lane = (e >> 3) & 63;
        int tile = (e >> 9) & 7;
        int ks   = (e >> 12) & 1;
        int gk   = e >> 13;                      // 0..17
        int g = gk / 9, k = gk - g * 9;
        int oc = tile * 16 + (lane & 15);
        int c  = ks * 32 + (lane >> 4) * 8 + j;
        wt2[e] = f2bf(w[((size_t)oc * Cn + g * Cgn + c) * KKn + k]);
    } else {
        int e = (blk - 1088) * 256 + t;          // [0,36864)
        int g  = e / 18432;
        int r  = e - g * 18432;
        int ks = r >> 10;
        int r2 = r & 1023;
        int nt = r2 >> 9;
        int lane = (r2 >> 3) & 63;
        int j  = r2 & 7;
        int tap = ks >> 1, chalf = ks & 1;
        int oc_l = nt * 16 + (lane & 15);
        int c = chalf * 32 + (lane >> 4) * 8 + j;
        float v = 0.f;
        if (oc_l < 27)
            v = ow[((size_t)(g * 27 + oc_l) * Cgn + c) * KKn + tap];
        owf[e] = f2bf(v);
    }
}

// ---------------------------------------------------------------------------
// Kernel G (R12): offset-conv + sampling + gather/bilinear, NO MFMA phase.
// R8-R11 post-mortem: the fused loop is convoy-bound — barriers synchronize
// all resident waves, which then burst scattered loads into one TA/L2 path;
// queueing inflates latency; no pipe exceeds 30%. Here the gk loop has NO
// barriers: iterations are independent, unroll-3 keeps ~12 loads in flight
// per wave, waves free-run -> scatter path runs at throughput, not latency.
// Output: val2[gk][p][64ch] bf16 (per-wave stores = 1KB contiguous).
// Same math as the fused kernel -> bit-identical val values.
// LDS: 9216 (s_cw) + 2304 (s_pk) + 3672 (s_om) = 15192 B.
// ---------------------------------------------------------------------------
__global__ __launch_bounds__(256, 4) void dcn_gather(const unsigned short* __restrict__ xt,
                                                     const unsigned short* __restrict__ owf,
                                                     const float* __restrict__ ob,
                                                     unsigned short* __restrict__ val2) {
    __shared__ float4 s_cw[18][32];
    __shared__ int    s_pk[18][32];
    __shared__ unsigned short s_om[54 * OMP];                    // [c54][pos]

    const int t  = threadIdx.x;
    const int id = blockIdx.x;               // [0, 1024)
    const int b  = id & 7;                   // XCD-aware: batch b lives on XCD b
    const int ho = (id >> 3) & 63;
    const int mh = id >> 9;                  // pos half 0/1

    const int lane = t & 63;
    const int wv   = t >> 6;                 // wave id 0..3
    const int lr   = lane & 15;
    const int lk   = (lane >> 4) * 8;
    const int q    = lane >> 4;

    const unsigned short* xb0 = xt + (size_t)b * (Hn * Wn * Cn);
    const short8 zz = {0, 0, 0, 0, 0, 0, 0, 0};

    // ---- P0: offset-conv GEMM for this half-row (proven, unchanged) ----
    {
        const int cg = wv >> 1;
        const int nh = wv & 1;
        const int oc_l = nh * 16 + lr;
        float bias = (oc_l < 27) ? ob[cg * 27 + oc_l] : 0.f;
        f32x4 oacc[2];
        oacc[0] = (f32x4){bias, bias, bias, bias};
        oacc[1] = (f32x4){bias, bias, bias, bias};

        const unsigned short* xb = xb0 + cg * Cgn;
        const unsigned short* wf = owf + (size_t)cg * 18432;

        for (int tap = 0; tap < 9; ++tap) {
            int ky = tap / 3, kx = tap - ky * 3;
            int y = ho - 2 + 2 * ky;
            if (y < 0 || y >= Hn) continue;  // wave-uniform skip (zero pad)
#pragma unroll
            for (int ch = 0; ch < 2; ++ch) {
                int kssl = tap * 2 + ch;
                short8 bv = *(const short8*)&wf[(size_t)kssl * 1024 + nh * 512 + lane * 8];
#pragma unroll
                for (int mt = 0; mt < 2; ++mt) {
                    int wo = mh * 32 + mt * 16 + lr;
                    int xc = wo - 2 + 2 * kx;
                    bool vx = (xc >= 0) & (xc < Wn);
                    int xcc = min(max(xc, 0), Wn - 1);
                    short8 av = *(const short8*)&xb[((size_t)y * Wn + xcc) * Cn + ch * 32 + lk];
                    av = vx ? av : zz;
                    oacc[mt] = __builtin_amdgcn_mfma_f32_16x16x32_bf16(av, bv, oacc[mt], 0, 0, 0);
                }
            }
        }
        if (oc_l < 27) {
            int c54 = cg * 27 + oc_l;
#pragma unroll
            for (int mt = 0; mt < 2; ++mt)
#pragma unroll
                for (int r = 0; r < 4; ++r)
                    s_om[c54 * OMP + mt * 16 + q * 4 + r] = f2bf(oacc[mt][r]);
        }
    }
    __syncthreads();

    // ---- P1: sampling params (proven, unchanged) ----
    for (int e = t; e < 18 * 32; e += 256) {
        int pos = e & 31;
        int wo  = mh * 32 + pos;
        int gk  = e >> 5;
        int g  = gk / 9, k = gk - g * 9;
        int ky = k / 3,  kx = k - ky * 3;
        float offy = bf2f(s_om[(g * 18 + k * 2 + 0) * OMP + pos]);
        float offx = bf2f(s_om[(g * 18 + k * 2 + 1) * OMP + pos]);
        float mk   = bf2f(s_om[(36 + g * 9 + k) * OMP + pos]);
        mk = 2.0f / (1.0f + __expf(-mk));

        float py = offy + (float)(ky * 2 + ho - 2);
        float px = offx + (float)(kx * 2 + wo - 2);
        float fy = floorf(py), fx = floorf(px);
        int   y0 = (int)fy,    x0 = (int)fx;
        float wy = py - fy,    wx = px - fx;

        bool vy0 = (y0 >= 0) & (y0 < Hn);
        bool vy1 = (y0 + 1 >= 0) & (y0 + 1 < Hn);
        bool vx0 = (x0 >= 0) & (x0 < Wn);
        bool vx1 = (x0 + 1 >= 0) & (x0 + 1 < Wn);
        float4 cw;
        cw.x = (vy0 & vx0) ? (1.f - wy) * (1.f - wx) * mk : 0.f;
        cw.y = (vy0 & vx1) ? (1.f - wy) * wx * mk : 0.f;
        cw.z = (vy1 & vx0) ? wy * (1.f - wx) * mk : 0.f;
        cw.w = (vy1 & vx1) ? wy * wx * mk : 0.f;

        int y0c = min(max(y0, 0), Hn - 1);
        int y1c = min(max(y0 + 1, 0), Hn - 1);
        int x0c = min(max(x0, 0), Wn - 1);
        int x1c = min(max(x0 + 1, 0), Wn - 1);
        s_cw[gk][pos] = cw;
        s_pk[gk][pos] = y0c | (y1c << 8) | (x0c << 16) | (x1c << 24);
    }
    __syncthreads();

    // ---- P2: barrier-free gather + bilinear, streamed to val2 ----
    const int pos = t >> 3;                  // position 0..31
    const int cq  = (t & 7) * 8;             // 8-ch chunk (group-local)
    const int pbase = b * 4096 + ho * 64 + mh * 32 + pos;

#pragma unroll 3
    for (int gk = 0; gk < 18; ++gk) {
        const int g = (gk >= 9) ? 1 : 0;
        float4 cw = s_cw[gk][pos];
        int pk  = s_pk[gk][pos];
        int y0c = pk & 255, y1c = (pk >> 8) & 255;
        int x0c = (pk >> 16) & 255, x1c = (pk >> 24) & 255;
        const unsigned short* xb = xb0 + g * Cgn + cq;
        short8 a00 = *(const short8*)&xb[((size_t)y0c * Wn + x0c) * Cn];
        short8 a01 = *(const short8*)&xb[((size_t)y0c * Wn + x1c) * Cn];
        short8 a10 = *(const short8*)&xb[((size_t)y1c * Wn + x0c) * Cn];
        short8 a11 = *(const short8*)&xb[((size_t)y1c * Wn + x1c) * Cn];
        short8 h0;
#pragma unroll
        for (int i = 0; i < 8; ++i) {
            float v = cw.x * bf2f((unsigned short)a00[i]) +
                      cw.y * bf2f((unsigned short)a01[i]) +
                      cw.z * bf2f((unsigned short)a10[i]) +
                      cw.w * bf2f((unsigned short)a11[i]);
            h0[i] = (short)f2bf(v);
        }
        *(short8*)&val2[((size_t)gk * 32768 + pbase) * 64 + cq] = h0;  // 1KB/wave contig
    }
}

// ---------------------------------------------------------------------------
// Kernel M (R12): clean bf16 MFMA GEMM. out[p, oc] = sum_K val2[K, p] * W.
// M=32 per block (grid 1024), N=128, K=1152 (18 gk x 64ch).
// Double-buffered LDS A-tile, ONE barrier per gk, T14 issue-early/write-late
// staging (stage load for gk+1 issues before gk's MFMAs). Accumulation order
// (gk asc, ks asc) identical to the fused kernel -> bit-identical output.
// LDS: 2 x 32 x 72 x 2 = 9216 B.
// ---------------------------------------------------------------------------
__global__ __launch_bounds__(256, 4) void dcn_gemm(const unsigned short* __restrict__ val2,
                                                   const unsigned short* __restrict__ wt2,
                                                   float* __restrict__ out) {
    __shared__ __align__(16) unsigned short s_a[2][32 * PITCH];

    const int t  = threadIdx.x;
    const int id = blockIdx.x;               // [0, 1024)
    const int b  = id & 7;                   // same XCD as producer blocks
    const int ho = (id >> 3) & 63;
    const int mh = id >> 9;

    const int lane = t & 63;
    const int wv   = t >> 6;
    const int lr   = lane & 15;
    const int lk   = (lane >> 4) * 8;
    const int q    = lane >> 4;

    const int p0 = b * 4096 + ho * 64 + mh * 32;
    const int sp = t >> 3;                   // stage: position 0..31
    const int sc = (t & 7) * 8;              // stage: 8-ch chunk

    f32x4 acc[2][2];
#pragma unroll
    for (int mt = 0; mt < 2; ++mt)
#pragma unroll
        for (int nt = 0; nt < 2; ++nt) acc[mt][nt] = (f32x4){0.f, 0.f, 0.f, 0.f};

    // prologue: stage gk=0 into buf 0 (per-wave 1KB contiguous load)
    {
        short8 v = *(const short8*)&val2[((size_t)0 * 32768 + p0 + sp) * 64 + sc];
        *(short8*)&s_a[0][sp * PITCH + sc] = v;
    }
    __syncthreads();

    for (int gk = 0; gk < 18; ++gk) {
        const int buf = gk & 1;

        // T14: issue next stage load EARLY (latency hides under MFMAs)
        short8 stg;
        if (gk < 17)
            stg = *(const short8*)&val2[((size_t)(gk + 1) * 32768 + p0 + sp) * 64 + sc];

        // B fragments for this gk (L2-hot)
        const unsigned short* wf = wt2 + (size_t)gk * 8192;
        short8 bfr[2][2];
#pragma unroll
        for (int ks = 0; ks < 2; ++ks)
#pragma unroll
            for (int nt = 0; nt < 2; ++nt)
                bfr[ks][nt] = *(const short8*)&wf[(size_t)(ks * 8 + wv * 2 + nt) * 512 + lane * 8];

        // MFMAs for this gk (reads s_a[buf])
#pragma unroll
        for (int ks = 0; ks < 2; ++ks) {
            short8 af[2];
#pragma unroll
            for (int mt = 0; mt < 2; ++mt)
                af[mt] = *(const short8*)&s_a[buf][(mt * 16 + lr) * PITCH + ks * 32 + lk];
#pragma unroll
            for (int mt = 0; mt < 2; ++mt)
#pragma unroll
                for (int nt = 0; nt < 2; ++nt)
                    acc[mt][nt] = __builtin_amdgcn_mfma_f32_16x16x32_bf16(
                        af[mt], bfr[ks][nt], acc[mt][nt], 0, 0, 0);
        }

        // write next tile late, into the other buffer
        if (gk < 17)
            *(short8*)&s_a[buf ^ 1][sp * PITCH + sc] = stg;
        __syncthreads();
    }

    // epilogue: identical addressing to the fused kernel
#pragma unroll
    for (int mt = 0; mt < 2; ++mt)
#pragma unroll
        for (int nt = 0; nt < 2; ++nt) {
            int oc = wv * 32 + nt * 16 + lr;
            int pr = mh * 32 + mt * 16 + q * 4;
            float4 v = {acc[mt][nt][0], acc[mt][nt][1], acc[mt][nt][2], acc[mt][nt][3]};
            *(float4*)&out[(((size_t)b * Con + oc) * HOn + ho) * WOn + pr] = v;
        }
}

// ---------------------------------------------------------------------------
// Fallback: proven fused kernel (48.6 us) — used only if workspace too small.
// ---------------------------------------------------------------------------
__global__ __launch_bounds__(256, 4) void dcn_fused(const unsigned short* __restrict__ xt,
                                                    const unsigned short* __restrict__ owf,
                                                    const float* __restrict__ ob,
                                                    const unsigned short* __restrict__ wt2,
                                                    float* __restrict__ out) {
    __shared__ __align__(16) unsigned short s_val[32 * PITCH];
    __shared__ float4 s_cw[18][32];
    __shared__ int    s_pk[18][32];
    __shared__ unsigned short s_om[54 * OMP];

    const int t  = threadIdx.x;
    const int id = blockIdx.x;
    const int b  = id & 7;
    const int ho = (id >> 3) & 63;
    const int mh = id >> 9;

    const int lane = t & 63;
    const int wv   = t >> 6;
    const int lr   = lane & 15;
    const int lk   = (lane >> 4) * 8;
    const int q    = lane >> 4;

    const unsigned short* xb0 = xt + (size_t)b * (Hn * Wn * Cn);
    const short8 zz = {0, 0, 0, 0, 0, 0, 0, 0};

    {
        const int cg = wv >> 1;
        const int nh = wv & 1;
        const int oc_l = nh * 16 + lr;
        float bias = (oc_l < 27) ? ob[cg * 27 + oc_l] : 0.f;
        f32x4 oacc[2];
        oacc[0] = (f32x4){bias, bias, bias, bias};
        oacc[1] = (f32x4){bias, bias, bias, bias};
        const unsigned short* xb = xb0 + cg * Cgn;
        const unsigned short* wf = owf + (size_t)cg * 18432;
        for (int tap = 0; tap < 9; ++tap) {
            int ky = tap / 3, kx = tap - ky * 3;
            int y = ho - 2 + 2 * ky;
            if (y < 0 || y >= Hn) continue;
#pragma unroll
            for (int ch = 0; ch < 2; ++ch) {
                int kssl = tap * 2 + ch;
                short8 bv = *(const short8*)&wf[(size_t)kssl * 1024 + nh * 512 + lane * 8];
#pragma unroll
                for (int mt = 0; mt < 2; ++mt) {
                    int wo = mh * 32 + mt * 16 + lr;
                    int xc = wo - 2 + 2 * kx;
                    bool vx = (xc >= 0) & (xc < Wn);
                    int xcc = min(max(xc, 0), Wn - 1);
                    short8 av = *(const short8*)&xb[((size_t)y * Wn + xcc) * Cn + ch * 32 + lk];
                    av = vx ? av : zz;
                    oacc[mt] = __builtin_amdgcn_mfma_f32_16x16x32_bf16(av, bv, oacc[mt], 0, 0, 0);
                }
            }
        }
        if (oc_l < 27) {
            int c54 = cg * 27 + oc_l;
#pragma unroll
            for (int mt = 0; mt < 2; ++mt)
#pragma unroll
                for (int r = 0; r < 4; ++r)
                    s_om[c54 * OMP + mt * 16 + q * 4 + r] = f2bf(oacc[mt][r]);
        }
    }
    __syncthreads();

    for (int e = t; e < 18 * 32; e += 256) {
        int pos = e & 31;
        int wo  = mh * 32 + pos;
        int gk  = e >> 5;
        int g  = gk / 9, k = gk - g * 9;
        int ky = k / 3,  kx = k - ky * 3;
        float offy = bf2f(s_om[(g * 18 + k * 2 + 0) * OMP + pos]);
        float offx = bf2f(s_om[(g * 18 + k * 2 + 1) * OMP + pos]);
        float mk   = bf2f(s_om[(36 + g * 9 + k) * OMP + pos]);
        mk = 2.0f / (1.0f + __expf(-mk));
        float py = offy + (float)(ky * 2 + ho - 2);
        float px = offx + (float)(kx * 2 + wo - 2);
        float fy = floorf(py), fx = floorf(px);
        int   y0 = (int)fy,    x0 = (int)fx;
        float wy = py - fy,    wx = px - fx;
        bool vy0 = (y0 >= 0) & (y0 < Hn);
        bool vy1 = (y0 + 1 >= 0) & (y0 + 1 < Hn);
        bool vx0 = (x0 >= 0) & (x0 < Wn);
        bool vx1 = (x0 + 1 >= 0) & (x0 + 1 < Wn);
        float4 cw;
        cw.x = (vy0 & vx0) ? (1.f - wy) * (1.f - wx) * mk : 0.f;
        cw.y = (vy0 & vx1) ? (1.f - wy) * wx * mk : 0.f;
        cw.z = (vy1 & vx0) ? wy * (1.f - wx) * mk : 0.f;
        cw.w = (vy1 & vx1) ? wy * wx * mk : 0.f;
        int y0c = min(max(y0, 0), Hn - 1);
        int y1c = min(max(y0 + 1, 0), Hn - 1);
        int x0c = min(max(x0, 0), Wn - 1);
        int x1c = min(max(x0 + 1, 0), Wn - 1);
        s_cw[gk][pos] = cw;
        s_pk[gk][pos] = y0c | (y1c << 8) | (x0c << 16) | (x1c << 24);
    }
    __syncthreads();

    const int pos = t >> 3;
    const int cq  = (t & 7) * 8;

    f32x4 acc[2][2];
#pragma unroll
    for (int mt = 0; mt < 2; ++mt)
#pragma unroll
        for (int nt = 0; nt < 2; ++nt) acc[mt][nt] = (f32x4){0.f, 0.f, 0.f, 0.f};

    for (int gk = 0; gk < 18; ++gk) {
        const unsigned short* wf = wt2 + (size_t)gk * 8192;
        short8 bfr[2][2];
#pragma unroll
        for (int ks = 0; ks < 2; ++ks)
#pragma unroll
            for (int nt = 0; nt < 2; ++nt)
                bfr[ks][nt] = *(const short8*)&wf[(size_t)(ks * 8 + wv * 2 + nt) * 512 + lane * 8];
        {
            const int g = gk / 9;
            float4 cw = s_cw[gk][pos];
            int pk  = s_pk[gk][pos];
            int y0c = pk & 255, y1c = (pk >> 8) & 255;
            int x0c = (pk >> 16) & 255, x1c = (pk >> 24) & 255;
            const unsigned short* xb = xb0 + g * Cgn + cq;
            short8 a00 = *(const short8*)&xb[((size_t)y0c * Wn + x0c) * Cn];
            short8 a01 = *(const short8*)&xb[((size_t)y0c * Wn + x1c) * Cn];
            short8 a10 = *(const short8*)&xb[((size_t)y1c * Wn + x0c) * Cn];
            short8 a11 = *(const short8*)&xb[((size_t)y1c * Wn + x1c) * Cn];
            short8 h0;
#pragma unroll
            for (int i = 0; i < 8; ++i) {
                float v = cw.x * bf2f((unsigned short)a00[i]) +
                          cw.y * bf2f((unsigned short)a01[i]) +
                          cw.z * bf2f((unsigned short)a10[i]) +
                          cw.w * bf2f((unsigned short)a11[i]);
                h0[i] = (short)f2bf(v);
            }
            *(short8*)&s_val[pos * PITCH + cq] = h0;
        }
        __syncthreads();
#pragma unroll
        for (int ks = 0; ks < 2; ++ks) {
            short8 af[2];
#pragma unroll
            for (int mt = 0; mt < 2; ++mt)
                af[mt] = *(const short8*)&s_val[(mt * 16 + lr) * PITCH + ks * 32 + lk];
#pragma unroll
            for (int mt = 0; mt < 2; ++mt)
#pragma unroll
                for (int nt = 0; nt < 2; ++nt)
                    acc[mt][nt] = __builtin_amdgcn_mfma_f32_16x16x32_bf16(
                        af[mt], bfr[ks][nt], acc[mt][nt], 0, 0, 0);
        }
        __syncthreads();
    }

#pragma unroll
    for (int mt = 0; mt < 2; ++mt)
#pragma unroll
        for (int nt = 0; nt < 2; ++nt) {
            int oc = wv * 32 + nt * 16 + lr;
            int pr = mh * 32 + mt * 16 + q * 4;
            float4 v = {acc[mt][nt][0], acc[mt][nt][1], acc[mt][nt][2], acc[mt][nt][3]};
            *(float4*)&out[(((size_t)b * Con + oc) * HOn + ho) * WOn + pr] = v;
        }
}

// ---------------------------------------------------------------------------
extern "C" void kernel_launch(void* const* d_in, const int* in_sizes, int n_in,
                              void* d_out, int out_size, void* d_ws, size_t ws_size,
                              hipStream_t stream) {
    const float* x  = (const float*)d_in[0];   // [8,128,64,64]
    const float* ow = (const float*)d_in[1];   // [54,64,3,3]
    const float* ob = (const float*)d_in[2];   // [54]
    const float* w  = (const float*)d_in[3];   // [128,128,3,3]
    float* out = (float*)d_out;                // [8,128,64,64]

    unsigned short* xt   = (unsigned short*)d_ws;
    unsigned short* wt2  = (unsigned short*)((char*)d_ws + XT_BYTES);
    unsigned short* owf  = (unsigned short*)((char*)d_ws + XT_BYTES + WT2_BYTES);
    unsigned short* val2 = (unsigned short*)((char*)d_ws + XT_BYTES + WT2_BYTES + OWF_BYTES);

    hipLaunchKernelGGL(prep, dim3(1232), dim3(256), 0, stream,
                       x, w, ow, xt, wt2, owf);

    if (ws_size >= WS_NEEDED) {
        hipLaunchKernelGGL(dcn_gather, dim3(1024), dim3(256), 0, stream,
                           xt, owf, ob, val2);
        hipLaunchKernelGGL(dcn_gemm, dim3(1024), dim3(256), 0, stream,
                           val2, wt2, out);
    } else {
        hipLaunchKernelGGL(dcn_fused, dim3(1024), dim3(256), 0, stream,
                           xt, owf, ob, wt2, out);
    }
}

// Round 5
// 122.417 us; speedup vs baseline: 1.0661x; 1.0661x over previous
//
#include <hip/hip_runtime.h>
#include <hip/hip_bf16.h>

// Problem constants
static constexpr int Bn = 8, Cn = 128, Hn = 64, Wn = 64, Con = 128;
static constexpr int KKn = 9, DGn = 2, Cgn = 64;
static constexpr int HOn = 64, WOn = 64;
static constexpr int PITCH = 72;     // bf16 row pitch for s_val rows
static constexpr int OMP3 = 66;      // s_om row pitch (shorts), 64 pos + pad

typedef short short8 __attribute__((ext_vector_type(8)));
typedef float f32x4  __attribute__((ext_vector_type(4)));

__device__ __forceinline__ unsigned short f2bf(float f) {
    unsigned u = __float_as_uint(f);
    u += 0x7fff + ((u >> 16) & 1);          // round-to-nearest-even
    return (unsigned short)(u >> 16);
}
__device__ __forceinline__ float bf2f(unsigned short h) {
    return __uint_as_float(((unsigned)h) << 16);
}

// ---------------------------------------------------------------------------
// Kernel P: merged prep (unchanged, proven).
// ---------------------------------------------------------------------------
__global__ __launch_bounds__(256) void prep(const float* __restrict__ x,
                                            const float* __restrict__ w,
                                            const float* __restrict__ ow,
                                            unsigned short* __restrict__ xt,
                                            unsigned short* __restrict__ wt2,
                                            unsigned short* __restrict__ owf) {
    __shared__ unsigned short s[128 * 64];       // 16 KB [c][x]
    const int blk = blockIdx.x;
    const int t = threadIdx.x;
    if (blk < 512) {
        const int b = blk & 7, y = blk >> 3;
#pragma unroll
        for (int i = 0; i < 32; ++i) {
            int e = t + i * 256;                 // [0,8192)
            int c = e >> 6, xc = e & 63;
            s[c * 64 + xc] = f2bf(x[(((size_t)b * Cn + c) * Hn + y) * Wn + xc]);
        }
        __syncthreads();
        unsigned short* dst = xt + ((size_t)(b * 64 + y) * 64) * 128;
#pragma unroll
        for (int i = 0; i < 4; ++i) {
            int e = t + i * 256;                 // short8 id [0,1024)
            int xc = e >> 4;
            int c0 = (e & 15) * 8;
            short8 v;
#pragma unroll
            for (int j = 0; j < 8; ++j) v[j] = (short)s[(c0 + j) * 64 + xc];
            *(short8*)&dst[(size_t)e * 8] = v;
        }
    } else if (blk < 1088) {
        int e    = (blk - 512) * 256 + t;        // [0,147456)
        int j    = e & 7;
        int lane = (e >> 3) & 63;
        int tile = (e >> 9) & 7;
        int ks   = (e >> 12) & 1;
        int gk   = e >> 13;                      // 0..17
        int g = gk / 9, k = gk - g * 9;
        int oc = tile * 16 + (lane & 15);
        int c  = ks * 32 + (lane >> 4) * 8 + j;
        wt2[e] = f2bf(w[((size_t)oc * Cn + g * Cgn + c) * KKn + k]);
    } else {
        int e = (blk - 1088) * 256 + t;          // [0,36864)
        int g  = e / 18432;
        int r  = e - g * 18432;
        int ks = r >> 10;
        int r2 = r & 1023;
        int nt = r2 >> 9;
        int lane = (r2 >> 3) & 63;
        int j  = r2 & 7;
        int tap = ks >> 1, chalf = ks & 1;
        int oc_l = nt * 16 + (lane & 15);
        int c = chalf * 32 + (lane >> 4) * 8 + j;
        float v = 0.f;
        if (oc_l < 27)
            v = ow[((size_t)(g * 27 + oc_l) * Cgn + c) * KKn + tap];
        owf[e] = f2bf(v);
    }
}

// ---------------------------------------------------------------------------
// Kernel 2 (R13): FULL-ROW fused kernel. M=64, 512 threads (8 waves),
// grid 512 = (b = id&7, ho = id>>3), 2 blocks/CU (16 waves/CU, same as R8).
//
// Theory (postdicts R8-R12): kernel is L2-fabric-BW-bound (~50% of 34.5TB/s;
// ~103MB/XCD per dispatch, half of it wt2 re-reads + corner gathers).
// This version halves the wt2 term: each of 8 waves owns ONE oc-16 tile
// (tile = wv), so the 16KB/gk wt2 slice is read once per block and serves
// 64 output positions instead of 32. -18.4MB/XCD (-18% total L2 bytes).
//
// P0: offset-conv, 8 waves = (cg, rh, nh); per-wave work identical to R8.
// P1: sampling params for 18x64 (gk,pos).
// P2: dbuf s_val, 1 barrier/gk; per wave: 4 corner loads + bilinear +
//     2 B-frag loads (1KB each, no duplication) + 8 MFMA.
// Accumulation order per output (gk asc, ks asc) unchanged -> bit-identical.
// LDS: 18432 (s_val x2) + 18432 (s_cw) + 4608 (s_pk) + 7128 (s_om) = 48600 B.
// ---------------------------------------------------------------------------
__global__ __launch_bounds__(512, 4) void dcn_fused(const unsigned short* __restrict__ xt,
                                                    const unsigned short* __restrict__ owf,
                                                    const float* __restrict__ ob,
                                                    const unsigned short* __restrict__ wt2,
                                                    float* __restrict__ out) {
    __shared__ __align__(16) unsigned short s_val[2][64 * PITCH];  // double buffer
    __shared__ float4 s_cw[18][64];
    __shared__ int    s_pk[18][64];
    __shared__ unsigned short s_om[54 * OMP3];                     // [c54][pos]

    const int t  = threadIdx.x;              // [0,512)
    const int id = blockIdx.x;               // [0,512)
    const int b  = id & 7;                   // XCD-aware: batch b -> XCD b (x_t slice 1MB, L2-resident)
    const int ho = id >> 3;                  // full output row

    const int lane = t & 63;
    const int wv   = t >> 6;                 // wave id 0..7
    const int lr   = lane & 15;              // MFMA row/col part
    const int lk   = (lane >> 4) * 8;        // MFMA k offset (shorts)
    const int q    = lane >> 4;              // D row quad

    const unsigned short* xb0 = xt + (size_t)b * (Hn * Wn * Cn);
    const short8 zz = {0, 0, 0, 0, 0, 0, 0, 0};

    // ---- P0: offset-conv GEMM for this full row ----
    // 8 waves = (cg = wv>>2, rh = (wv>>1)&1, nh = wv&1); per wave M=32 rows
    // (rh half), oc-16 block nh. Same math/accumulation as R8's P0.
    {
        const int cg = wv >> 2;              // conv/deform group
        const int rh = (wv >> 1) & 1;        // row half (pos base rh*32)
        const int nh = wv & 1;               // oc 16-block
        const int oc_l = nh * 16 + lr;
        float bias = (oc_l < 27) ? ob[cg * 27 + oc_l] : 0.f;
        f32x4 oacc[2];
        oacc[0] = (f32x4){bias, bias, bias, bias};
        oacc[1] = (f32x4){bias, bias, bias, bias};

        const unsigned short* xb = xb0 + cg * Cgn;
        const unsigned short* wf = owf + (size_t)cg * 18432;

        for (int tap = 0; tap < 9; ++tap) {
            int ky = tap / 3, kx = tap - ky * 3;
            int y = ho - 2 + 2 * ky;
            if (y < 0 || y >= Hn) continue;  // wave-uniform skip (zero pad)
#pragma unroll
            for (int ch = 0; ch < 2; ++ch) {
                int kssl = tap * 2 + ch;
                short8 bv = *(const short8*)&wf[(size_t)kssl * 1024 + nh * 512 + lane * 8];
#pragma unroll
                for (int mt = 0; mt < 2; ++mt) {
                    int wo = rh * 32 + mt * 16 + lr;
                    int xc = wo - 2 + 2 * kx;
                    bool vx = (xc >= 0) & (xc < Wn);
                    int xcc = min(max(xc, 0), Wn - 1);
                    short8 av = *(const short8*)&xb[((size_t)y * Wn + xcc) * Cn + ch * 32 + lk];
                    av = vx ? av : zz;
                    oacc[mt] = __builtin_amdgcn_mfma_f32_16x16x32_bf16(av, bv, oacc[mt], 0, 0, 0);
                }
            }
        }
        if (oc_l < 27) {
            int c54 = cg * 27 + oc_l;
#pragma unroll
            for (int mt = 0; mt < 2; ++mt)
#pragma unroll
                for (int r = 0; r < 4; ++r)
                    s_om[c54 * OMP3 + rh * 32 + mt * 16 + q * 4 + r] = f2bf(oacc[mt][r]);
        }
    }
    __syncthreads();

    // ---- P1: sampling params for all (gk, pos) of this row ----
    for (int e = t; e < 18 * 64; e += 512) {
        int pos = e & 63;
        int wo  = pos;
        int gk  = e >> 6;
        int g  = gk / 9, k = gk - g * 9;
        int ky = k / 3,  kx = k - ky * 3;
        float offy = bf2f(s_om[(g * 18 + k * 2 + 0) * OMP3 + pos]);
        float offx = bf2f(s_om[(g * 18 + k * 2 + 1) * OMP3 + pos]);
        float mk   = bf2f(s_om[(36 + g * 9 + k) * OMP3 + pos]);
        mk = 2.0f / (1.0f + __expf(-mk));

        float py = offy + (float)(ky * 2 + ho - 2);
        float px = offx + (float)(kx * 2 + wo - 2);
        float fy = floorf(py), fx = floorf(px);
        int   y0 = (int)fy,    x0 = (int)fx;
        float wy = py - fy,    wx = px - fx;

        bool vy0 = (y0 >= 0) & (y0 < Hn);
        bool vy1 = (y0 + 1 >= 0) & (y0 + 1 < Hn);
        bool vx0 = (x0 >= 0) & (x0 < Wn);
        bool vx1 = (x0 + 1 >= 0) & (x0 + 1 < Wn);
        float4 cw;
        cw.x = (vy0 & vx0) ? (1.f - wy) * (1.f - wx) * mk : 0.f;
        cw.y = (vy0 & vx1) ? (1.f - wy) * wx * mk : 0.f;
        cw.z = (vy1 & vx0) ? wy * (1.f - wx) * mk : 0.f;
        cw.w = (vy1 & vx1) ? wy * wx * mk : 0.f;

        int y0c = min(max(y0, 0), Hn - 1);
        int y1c = min(max(y0 + 1, 0), Hn - 1);
        int x0c = min(max(x0, 0), Wn - 1);
        int x1c = min(max(x0 + 1, 0), Wn - 1);
        s_cw[gk][pos] = cw;
        s_pk[gk][pos] = y0c | (y1c << 8) | (x0c << 16) | (x1c << 24);
    }
    __syncthreads();

    // ---- P2: gather + MFMA loop, dbuf, one barrier per gk ----
    const int pos = t >> 3;                  // gather: position 0..63
    const int cq  = (t & 7) * 8;             // gather: 8-ch chunk (group-local)

    f32x4 acc[4];                            // mt 0..3 (rows mt*16), oc tile = wv
#pragma unroll
    for (int mt = 0; mt < 4; ++mt) acc[mt] = (f32x4){0.f, 0.f, 0.f, 0.f};

    for (int gk = 0; gk < 18; ++gk) {
        // ---- gather: 4 corners x 8 channels, each pos by 8 threads ----
        {
            const int g = (gk >= 9) ? 1 : 0;
            float4 cw = s_cw[gk][pos];
            int pk  = s_pk[gk][pos];
            int y0c = pk & 255, y1c = (pk >> 8) & 255;
            int x0c = (pk >> 16) & 255, x1c = (pk >> 24) & 255;
            const unsigned short* xb = xb0 + g * Cgn + cq;
            short8 a00 = *(const short8*)&xb[((size_t)y0c * Wn + x0c) * Cn];
            short8 a01 = *(const short8*)&xb[((size_t)y0c * Wn + x1c) * Cn];
            short8 a10 = *(const short8*)&xb[((size_t)y1c * Wn + x0c) * Cn];
            short8 a11 = *(const short8*)&xb[((size_t)y1c * Wn + x1c) * Cn];
            short8 h0;
#pragma unroll
            for (int i = 0; i < 8; ++i) {
                float v = cw.x * bf2f((unsigned short)a00[i]) +
                          cw.y * bf2f((unsigned short)a01[i]) +
                          cw.z * bf2f((unsigned short)a10[i]) +
                          cw.w * bf2f((unsigned short)a11[i]);
                h0[i] = (short)f2bf(v);
            }
            *(short8*)&s_val[gk & 1][pos * PITCH + cq] = h0;
        }
        __syncthreads();   // s_val[gk&1] ready; re-written only at gk+2 (post next barrier)

        // ---- B frags: wave wv owns oc tile wv -> slice read ONCE per block ----
        const unsigned short* wf = wt2 + (size_t)gk * 8192;
#pragma unroll
        for (int ks = 0; ks < 2; ++ks) {
            short8 bfr = *(const short8*)&wf[(size_t)(ks * 8 + wv) * 512 + lane * 8];
#pragma unroll
            for (int mt = 0; mt < 4; ++mt) {
                short8 af = *(const short8*)&s_val[gk & 1][(mt * 16 + lr) * PITCH + ks * 32 + lk];
                acc[mt] = __builtin_amdgcn_mfma_f32_16x16x32_bf16(af, bfr, acc[mt], 0, 0, 0);
            }
        }
    }

    // ---- epilogue: oc = wv*16 + lr; rows mt*16 + q*4 ----
#pragma unroll
    for (int mt = 0; mt < 4; ++mt) {
        int oc = wv * 16 + lr;
        int p0 = mt * 16 + q * 4;
        float4 v = {acc[mt][0], acc[mt][1], acc[mt][2], acc[mt][3]};
        *(float4*)&out[(((size_t)b * Con + oc) * HOn + ho) * WOn + p0] = v;
    }
}

// ---------------------------------------------------------------------------
extern "C" void kernel_launch(void* const* d_in, const int* in_sizes, int n_in,
                              void* d_out, int out_size, void* d_ws, size_t ws_size,
                              hipStream_t stream) {
    const float* x  = (const float*)d_in[0];   // [8,128,64,64]
    const float* ow = (const float*)d_in[1];   // [54,64,3,3]
    const float* ob = (const float*)d_in[2];   // [54]
    const float* w  = (const float*)d_in[3];   // [128,128,3,3]
    float* out = (float*)d_out;                // [8,128,64,64]

    // ws: x_t bf16 8,388,608 | wt2 294,912 | owf 73,728
    unsigned short* xt  = (unsigned short*)d_ws;
    unsigned short* wt2 = (unsigned short*)((char*)d_ws + 8388608);
    unsigned short* owf = (unsigned short*)((char*)d_ws + 8388608 + 294912);

    hipLaunchKernelGGL(prep, dim3(1232), dim3(256), 0, stream,
                       x, w, ow, xt, wt2, owf);
    hipLaunchKernelGGL(dcn_fused, dim3(512), dim3(512), 0, stream,
                       xt, owf, ob, wt2, out);
}